// Round 6
// baseline (383.054 us; speedup 1.0000x reference)
//
#include <hip/hip_runtime.h>
#include <math.h>

#define NXg 128
#define NYg 128
#define NTg 64
#define SEQ 128
#define DIM 64
#define NH 4
#define DHd 16
#define DFFd 128
#define NLAYER 2
#define EPSf 1e-5f

typedef _Float16 f16x8 __attribute__((ext_vector_type(8)));
typedef _Float16 f16x4 __attribute__((ext_vector_type(4)));
typedef __fp16 fp16x2 __attribute__((ext_vector_type(2)));
typedef float f32x4 __attribute__((ext_vector_type(4)));

#define MFMA16(a, b, c) __builtin_amdgcn_mfma_f32_16x16x32_f16(a, b, c, 0, 0, 0)

union FragU { int d[4]; f16x8 v; };
union H4U  { int d[2]; f16x4 v; };

__device__ __forceinline__ int pk2(float a, float b) {
  union { fp16x2 h; int i; } u;
  u.h = __builtin_amdgcn_cvt_pkrtz(a, b);
  return u.i;
}

__device__ __forceinline__ f16x8 zero8() {
  f16x8 z;
#pragma unroll
  for (int i = 0; i < 8; ++i) z[i] = (_Float16)0.0f;
  return z;
}
__device__ __forceinline__ f16x8 ld8(const _Float16* p) { return *(const f16x8*)p; }

// Build a K=16 (zero-padded to 32) B-fragment from a C-layout f32x4:
// input d4[jr] = T[dh=quad*4+jr][q=l15]; output B[k=quad*8+j][n=l15].
__device__ __forceinline__ f16x8 frag_k16(f32x4 d4, int quad, int l15) {
  int p0 = pk2(d4[0], d4[1]);
  int p1 = pk2(d4[2], d4[3]);
  int slA = ((2 * quad) * 16 + l15) & 63;
  int slB = ((2 * quad + 1) * 16 + l15) & 63;
  FragU u;
  u.d[0] = __shfl(p0, slA, 64);
  u.d[1] = __shfl(p1, slA, 64);
  u.d[2] = __shfl(p0, slB, 64);
  u.d[3] = __shfl(p1, slB, 64);
  if (quad >= 2) { u.d[0] = 0; u.d[1] = 0; u.d[2] = 0; u.d[3] = 0; }
  return u.v;
}

// Build a K=64 B-fragment (tile kt of 2) from register X:
// pk[mt][0..1] = packed pairs of X[f=mt*16+quad*4+{0..3}][q=l15].
__device__ __forceinline__ f16x8 frag_k64(const int pk[4][2], int kt, int quad, int l15) {
  const int slA = (2 * (quad & 1)) * 16 + l15;
  const int slB = (2 * (quad & 1) + 1) * 16 + l15;
  const bool hi = quad >= 2;  // selects mt = 2kt+1
  int a0 = __shfl(pk[2 * kt][0], slA, 64), b0 = __shfl(pk[2 * kt + 1][0], slA, 64);
  int a1 = __shfl(pk[2 * kt][1], slA, 64), b1 = __shfl(pk[2 * kt + 1][1], slA, 64);
  int a2 = __shfl(pk[2 * kt][0], slB, 64), b2 = __shfl(pk[2 * kt + 1][0], slB, 64);
  int a3 = __shfl(pk[2 * kt][1], slB, 64), b3 = __shfl(pk[2 * kt + 1][1], slB, 64);
  FragU u;
  u.d[0] = hi ? b0 : a0;
  u.d[1] = hi ? b1 : a1;
  u.d[2] = hi ? b2 : a2;
  u.d[3] = hi ? b3 : a3;
  return u.v;
}

// residual + LayerNorm on register X, one qt tile.
// acc[mt][jr], Xq[mt][jr] hold [f=mt*16+quad*4+jr][q=l15].
__device__ __forceinline__ void res_ln_qt(const f32x4 acc[4], f32x4 Xq[4],
                                          const float* __restrict__ bias,
                                          const float* __restrict__ lns,
                                          const float* __restrict__ lnb,
                                          int quad) {
  float v[4][4];
  float s = 0.f;
#pragma unroll
  for (int mt = 0; mt < 4; ++mt) {
    f32x4 bb = *(const f32x4*)(bias + mt * 16 + quad * 4);
#pragma unroll
    for (int jr = 0; jr < 4; ++jr) {
      v[mt][jr] = acc[mt][jr] + bb[jr] + Xq[mt][jr];
      s += v[mt][jr];
    }
  }
  s += __shfl_xor(s, 16, 64);
  s += __shfl_xor(s, 32, 64);
  const float mu = s * (1.0f / 64.0f);
  float q2 = 0.f;
#pragma unroll
  for (int mt = 0; mt < 4; ++mt)
#pragma unroll
    for (int jr = 0; jr < 4; ++jr) { float d = v[mt][jr] - mu; q2 = fmaf(d, d, q2); }
  q2 += __shfl_xor(q2, 16, 64);
  q2 += __shfl_xor(q2, 32, 64);
  const float rstd = rsqrtf(q2 * (1.0f / 64.0f) + EPSf);
#pragma unroll
  for (int mt = 0; mt < 4; ++mt) {
    f32x4 sv = *(const f32x4*)(lns + mt * 16 + quad * 4);
    f32x4 bv = *(const f32x4*)(lnb + mt * 16 + quad * 4);
#pragma unroll
    for (int jr = 0; jr < 4; ++jr)
      Xq[mt][jr] = fmaf((v[mt][jr] - mu) * rstd, sv[jr], bv[jr]);
  }
}

__global__ void prep_weights(const float* __restrict__ qkv_w,
                             const float* __restrict__ out_w,
                             const float* __restrict__ ff1_w,
                             const float* __restrict__ ff2_w,
                             _Float16* __restrict__ wsH) {
  int i = blockIdx.x * 256 + threadIdx.x;
  if (i < 24576) wsH[i] = (_Float16)qkv_w[i];
  else if (i < 32768) wsH[i] = (_Float16)out_w[i - 24576];
  else if (i < 49152) wsH[i] = (_Float16)ff1_w[i - 32768];
  else if (i < 65536) wsH[i] = (_Float16)ff2_w[i - 49152];
}

// ---------------------------------------------------------------------------
// Fused FieldFormer block: X/Q/O/P-normalization in registers, only K, V and
// P/FF-hidden in LDS (45.3 KB -> 3 blocks/CU). 256 thr = 4 waves per query.
// ---------------------------------------------------------------------------
__global__ __launch_bounds__(256, 3)
void fieldformer_mfma(const int* __restrict__ q_lin_idx,
                      const int* __restrict__ offsets_ijk,
                      const float* __restrict__ coords,
                      const float* __restrict__ vals,
                      const float* __restrict__ log_gammas,
                      const float* __restrict__ proj_w,
                      const float* __restrict__ proj_b,
                      const float* __restrict__ qkv_b,
                      const float* __restrict__ out_b,
                      const float* __restrict__ ln1_s,
                      const float* __restrict__ ln1_b,
                      const float* __restrict__ ff1_b,
                      const float* __restrict__ ff2_b,
                      const float* __restrict__ ln2_s,
                      const float* __restrict__ ln2_b,
                      const float* __restrict__ head_ln_s,
                      const float* __restrict__ head_ln_b,
                      const float* __restrict__ head1_w,
                      const float* __restrict__ head1_b,
                      const float* __restrict__ head2_w,
                      const float* __restrict__ head2_b,
                      const _Float16* __restrict__ wH,
                      float* __restrict__ out) {
  __shared__ __align__(16) _Float16 sPH[128 * 136];  // P / FF-hidden [tok][136]; X staging in phase 0
  __shared__ __align__(16) _Float16 sK[128 * 24];    // K [tok][24]; head scratch at the end
  __shared__ __align__(16) _Float16 sV[16 * 136];    // V^T [dh][136]

  const int tid = threadIdx.x;
  const int wv = tid >> 6;
  const int lane = tid & 63;
  const int quad = lane >> 4;
  const int l15 = lane & 15;
  const int b = blockIdx.x;

  // ---------------- phase 0: tokens -> proj -> sPH staging -> X regs ------
  {
    const int row = tid >> 1, hf = tid & 1;
    const int q = q_lin_idx[b];
    const int qi = q / (NYg * NTg);
    const int qrem = q - qi * (NYg * NTg);
    const int qj = qrem / NTg;
    const int qk = qrem - qj * NTg;
    const int di = offsets_ijk[row * 3 + 0];
    const int dj = offsets_ijk[row * 3 + 1];
    const int dk = offsets_ijk[row * 3 + 2];
    const int I = (qi + di) % NXg;
    const int J = (qj + dj) % NYg;
    int T = qk + dk; T = T < 0 ? 0 : (T > NTg - 1 ? NTg - 1 : T);
    const int nb = I * (NYg * NTg) + J * NTg + T;
    const float qx = coords[q * 3 + 0], qy = coords[q * 3 + 1], qz = coords[q * 3 + 2];
    const float nx_ = coords[nb * 3 + 0], ny_ = coords[nb * 3 + 1], nz_ = coords[nb * 3 + 2];
    float ax = nx_ - qx + 1.0f; ax -= 2.0f * floorf(ax * 0.5f); ax -= 1.0f;
    float ay = ny_ - qy + 1.0f; ay -= 2.0f * floorf(ay * 0.5f); ay -= 1.0f;
    const float at = nz_ - qz;
    float tok[6];
    tok[0] = ax * expf(log_gammas[0]);
    tok[1] = ay * expf(log_gammas[1]);
    tok[2] = at * expf(log_gammas[2]);
    tok[3] = vals[nb * 3 + 0];
    tok[4] = vals[nb * 3 + 1];
    tok[5] = vals[nb * 3 + 2];
#pragma unroll
    for (int ci = 0; ci < 32; ++ci) {
      const int c = hf * 32 + ci;
      const float* w = proj_w + c * 6;
      float a = proj_b[c];
      a = fmaf(tok[0], w[0], a); a = fmaf(tok[1], w[1], a);
      a = fmaf(tok[2], w[2], a); a = fmaf(tok[3], w[3], a);
      a = fmaf(tok[4], w[4], a); a = fmaf(tok[5], w[5], a);
      sPH[row * 136 + c] = (_Float16)a;
    }
  }
  __syncthreads();

  // X registers: X[qt][mt][jr] = X[f=mt*16+quad*4+jr][q=(wv*2+qt)*16+l15]
  f32x4 X[2][4];
#pragma unroll
  for (int qt = 0; qt < 2; ++qt) {
    const int q = (wv * 2 + qt) * 16 + l15;
#pragma unroll
    for (int mt = 0; mt < 4; ++mt) {
      f16x4 t = *(const f16x4*)(sPH + q * 136 + mt * 16 + quad * 4);
      X[qt][mt] = f32x4{(float)t[0], (float)t[1], (float)t[2], (float)t[3]};
    }
  }

  // ---------------- transformer layers ------------------------------------
  for (int l = 0; l < NLAYER; ++l) {
    const _Float16* qkvH = wH + l * 192 * 64;
    const _Float16* woutH = wH + 24576 + l * 64 * 64;
    const _Float16* ff1H = wH + 32768 + l * 128 * 64;
    const _Float16* ff2H = wH + 49152 + l * 64 * 128;
    const float* bqkv = qkv_b + l * 192;

    // X^T B-fragments from registers (reused by all heads)
    f16x8 bxf[2][2];
#pragma unroll
    for (int qt = 0; qt < 2; ++qt) {
      int pkx[4][2];
#pragma unroll
      for (int mt = 0; mt < 4; ++mt) {
        pkx[mt][0] = pk2(X[qt][mt][0], X[qt][mt][1]);
        pkx[mt][1] = pk2(X[qt][mt][2], X[qt][mt][3]);
      }
#pragma unroll
      for (int kt = 0; kt < 2; ++kt) bxf[qt][kt] = frag_k64(pkx, kt, quad, l15);
    }

    f32x4 y2[2][4];  // attention out-proj accumulator
#pragma unroll
    for (int qt = 0; qt < 2; ++qt)
#pragma unroll
      for (int mt = 0; mt < 4; ++mt) y2[qt][mt] = f32x4{0.f, 0.f, 0.f, 0.f};

    for (int h = 0; h < NH; ++h) {
      // ---- Q^T/K^T/V^T = W * X^T ----
      f32x4 dq[2] = {f32x4{0.f,0.f,0.f,0.f}, f32x4{0.f,0.f,0.f,0.f}};
      f32x4 dk[2] = {f32x4{0.f,0.f,0.f,0.f}, f32x4{0.f,0.f,0.f,0.f}};
      f32x4 dv[2] = {f32x4{0.f,0.f,0.f,0.f}, f32x4{0.f,0.f,0.f,0.f}};
#pragma unroll
      for (int kt = 0; kt < 2; ++kt) {
        f16x8 awq = ld8(qkvH + (h * 16 + l15) * 64 + kt * 32 + quad * 8);
        f16x8 awk = ld8(qkvH + (64 + h * 16 + l15) * 64 + kt * 32 + quad * 8);
        f16x8 awv = ld8(qkvH + (128 + h * 16 + l15) * 64 + kt * 32 + quad * 8);
#pragma unroll
        for (int qt = 0; qt < 2; ++qt) {
          dq[qt] = MFMA16(awq, bxf[qt][kt], dq[qt]);
          dk[qt] = MFMA16(awk, bxf[qt][kt], dk[qt]);
          dv[qt] = MFMA16(awv, bxf[qt][kt], dv[qt]);
        }
      }
      f16x8 bqf[2];
      {
        const f32x4 bq4 = *(const f32x4*)(bqkv + h * 16 + quad * 4);
        const f32x4 bk4 = *(const f32x4*)(bqkv + 64 + h * 16 + quad * 4);
        const f32x4 bv4 = *(const f32x4*)(bqkv + 128 + h * 16 + quad * 4);
#pragma unroll
        for (int qt = 0; qt < 2; ++qt) {
          const int q = (wv * 2 + qt) * 16 + l15;
          H4U k4;
          k4.d[0] = pk2(dk[qt][0] + bk4[0], dk[qt][1] + bk4[1]);
          k4.d[1] = pk2(dk[qt][2] + bk4[2], dk[qt][3] + bk4[3]);
          *(f16x4*)(sK + q * 24 + quad * 4) = k4.v;
#pragma unroll
          for (int jr = 0; jr < 4; ++jr)
            sV[(quad * 4 + jr) * 136 + q] = (_Float16)(dv[qt][jr] + bv4[jr]);
          f32x4 qv;
#pragma unroll
          for (int jr = 0; jr < 4; ++jr) qv[jr] = (dq[qt][jr] + bq4[jr]) * 0.25f;
          bqf[qt] = frag_k16(qv, quad, l15);  // Q stays in registers
        }
      }
      __syncthreads();  // K/V visible to all waves

#pragma unroll
      for (int qt = 0; qt < 2; ++qt) {
        const int q = (wv * 2 + qt) * 16 + l15;
        // scores S^T (K=16 pad 32)
        f32x4 sc[8];
#pragma unroll
        for (int mt = 0; mt < 8; ++mt) sc[mt] = f32x4{0.f, 0.f, 0.f, 0.f};
#pragma unroll
        for (int mt = 0; mt < 8; ++mt) {
          f16x8 ak = (quad < 2) ? ld8(sK + (mt * 16 + l15) * 24 + quad * 8) : zero8();
          sc[mt] = MFMA16(ak, bqf[qt], sc[mt]);
        }
        // softmax, shift-free (softmax is shift-invariant; scores are O(1))
        float s0 = 0.f;
#pragma unroll
        for (int mt = 0; mt < 8; ++mt)
#pragma unroll
          for (int jr = 0; jr < 4; ++jr) {
            float e = __expf(sc[mt][jr]);
            sc[mt][jr] = e;
            s0 += e;
          }
        s0 += __shfl_xor(s0, 16, 64);
        s0 += __shfl_xor(s0, 32, 64);
        const float inv = 1.0f / s0;
        // unnormalized P -> LDS (own rows, b64)
#pragma unroll
        for (int mt = 0; mt < 8; ++mt) {
          H4U pp;
          pp.d[0] = pk2(sc[mt][0], sc[mt][1]);
          pp.d[1] = pk2(sc[mt][2], sc[mt][3]);
          *(f16x4*)(sPH + q * 136 + mt * 16 + quad * 4) = pp.v;
        }
        // O^T = V^T * P^T, then normalize by row-sum
        f32x4 ov = f32x4{0.f, 0.f, 0.f, 0.f};
#pragma unroll
        for (int kt = 0; kt < 4; ++kt) {
          f16x8 av = ld8(sV + l15 * 136 + kt * 32 + quad * 8);
          f16x8 bp = ld8(sPH + q * 136 + kt * 32 + quad * 8);
          ov = MFMA16(av, bp, ov);
        }
#pragma unroll
        for (int jr = 0; jr < 4; ++jr) ov[jr] *= inv;
        // out-proj partial: Y^T += Wout_h * O_h^T (O frag from registers)
        f16x8 bof = frag_k16(ov, quad, l15);
#pragma unroll
        for (int mt = 0; mt < 4; ++mt) {
          f16x8 aw = (quad < 2) ? ld8(woutH + (mt * 16 + l15) * 64 + h * 16 + quad * 8)
                                : zero8();
          y2[qt][mt] = MFMA16(aw, bof, y2[qt][mt]);
        }
      }
      __syncthreads();  // all sK/sV reads done; next head may overwrite
    }  // heads

    // ---- attention epilogue: bias + residual + LN1 (registers) ----
#pragma unroll
    for (int qt = 0; qt < 2; ++qt)
      res_ln_qt(y2[qt], X[qt], out_b + l * 64, ln1_s + l * 64, ln1_b + l * 64, quad);

    // rebuild X fragments post-LN1
#pragma unroll
    for (int qt = 0; qt < 2; ++qt) {
      int pkx[4][2];
#pragma unroll
      for (int mt = 0; mt < 4; ++mt) {
        pkx[mt][0] = pk2(X[qt][mt][0], X[qt][mt][1]);
        pkx[mt][1] = pk2(X[qt][mt][2], X[qt][mt][3]);
      }
#pragma unroll
      for (int kt = 0; kt < 2; ++kt) bxf[qt][kt] = frag_k64(pkx, kt, quad, l15);
    }

    // ---- FF1: H^T = relu(W1 * X^T + b1) -> sPH (own rows) ----
#pragma unroll
    for (int qt = 0; qt < 2; ++qt) {
      const int q = (wv * 2 + qt) * 16 + l15;
      f32x4 f8[8];
#pragma unroll
      for (int mt = 0; mt < 8; ++mt) f8[mt] = f32x4{0.f, 0.f, 0.f, 0.f};
#pragma unroll
      for (int kt = 0; kt < 2; ++kt)
#pragma unroll
        for (int mt = 0; mt < 8; ++mt) {
          f16x8 aw = ld8(ff1H + (mt * 16 + l15) * 64 + kt * 32 + quad * 8);
          f8[mt] = MFMA16(aw, bxf[qt][kt], f8[mt]);
        }
      const float* b1 = ff1_b + l * 128;
#pragma unroll
      for (int mt = 0; mt < 8; ++mt) {
        f32x4 bb = *(const f32x4*)(b1 + mt * 16 + quad * 4);
        H4U hh;
        hh.d[0] = pk2(fmaxf(f8[mt][0] + bb[0], 0.f), fmaxf(f8[mt][1] + bb[1], 0.f));
        hh.d[1] = pk2(fmaxf(f8[mt][2] + bb[2], 0.f), fmaxf(f8[mt][3] + bb[3], 0.f));
        *(f16x4*)(sPH + q * 136 + mt * 16 + quad * 4) = hh.v;
      }
    }

    // ---- FF2 + residual + LN2 (registers) ----
#pragma unroll
    for (int qt = 0; qt < 2; ++qt) {
      const int q = (wv * 2 + qt) * 16 + l15;
      f32x4 g4[4];
#pragma unroll
      for (int mt = 0; mt < 4; ++mt) g4[mt] = f32x4{0.f, 0.f, 0.f, 0.f};
#pragma unroll
      for (int kt = 0; kt < 4; ++kt) {
        f16x8 bh = ld8(sPH + q * 136 + kt * 32 + quad * 8);
#pragma unroll
        for (int mt = 0; mt < 4; ++mt) {
          f16x8 aw = ld8(ff2H + (mt * 16 + l15) * 128 + kt * 32 + quad * 8);
          g4[mt] = MFMA16(aw, bh, g4[mt]);
        }
      }
      res_ln_qt(g4, X[qt], ff2_b + l * 64, ln2_s + l * 64, ln2_b + l * 64, quad);
    }
  }  // layers

  // ---------------- head: mean over S, LN, gelu-MLP -> 3 outputs ----------
  __syncthreads();  // sK free for scratch
  {
    float* pf = (float*)sK;   // 256 partials
    float* gsc = pf + 256;
    float* asc = gsc + 64;
    // column sums from register X: in-lane qt, shfl over l15
    f32x4 cs[4];
#pragma unroll
    for (int mt = 0; mt < 4; ++mt) cs[mt] = X[0][mt] + X[1][mt];
#pragma unroll
    for (int d = 1; d <= 8; d <<= 1)
#pragma unroll
      for (int mt = 0; mt < 4; ++mt)
#pragma unroll
        for (int jr = 0; jr < 4; ++jr) cs[mt][jr] += __shfl_xor(cs[mt][jr], d, 64);
    if (l15 == 0) {
#pragma unroll
      for (int mt = 0; mt < 4; ++mt)
        *(f32x4*)(pf + wv * 64 + mt * 16 + quad * 4) = cs[mt];
    }
    __syncthreads();
    if (tid < 64) {
      const float hm = (pf[tid] + pf[64 + tid] + pf[128 + tid] + pf[192 + tid]) * (1.0f / 128.0f);
      float t = hm;
      t += __shfl_xor(t, 1, 64);  t += __shfl_xor(t, 2, 64);
      t += __shfl_xor(t, 4, 64);  t += __shfl_xor(t, 8, 64);
      t += __shfl_xor(t, 16, 64); t += __shfl_xor(t, 32, 64);
      const float mu = t * (1.0f / 64.0f);
      const float dv = hm - mu;
      float v2 = dv * dv;
      v2 += __shfl_xor(v2, 1, 64);  v2 += __shfl_xor(v2, 2, 64);
      v2 += __shfl_xor(v2, 4, 64);  v2 += __shfl_xor(v2, 8, 64);
      v2 += __shfl_xor(v2, 16, 64); v2 += __shfl_xor(v2, 32, 64);
      const float var = v2 * (1.0f / 64.0f);
      gsc[tid] = fmaf(dv * rsqrtf(var + EPSf), head_ln_s[tid], head_ln_b[tid]);
    }
    __syncthreads();
    if (tid < 64) {
      float z = head1_b[tid];
      for (int k = 0; k < 64; ++k) z = fmaf(gsc[k], head1_w[tid * 64 + k], z);
      asc[tid] = 0.5f * z * (1.0f + erff(z * 0.70710678118654752f));
    }
    __syncthreads();
    if (tid < 3) {
      float z = head2_b[tid];
      for (int k = 0; k < 64; ++k) z = fmaf(asc[k], head2_w[tid * 64 + k], z);
      out[b * 3 + tid] = z;
    }
  }
}

extern "C" void kernel_launch(void* const* d_in, const int* in_sizes, int n_in,
                              void* d_out, int out_size, void* d_ws, size_t ws_size,
                              hipStream_t stream) {
  (void)n_in; (void)ws_size; (void)out_size;
  const int B = in_sizes[0];
  _Float16* wsH = (_Float16*)d_ws;  // 65536 halves = 128 KB

  prep_weights<<<dim3(256), dim3(256), 0, stream>>>(
      (const float*)d_in[7],   // qkv_w
      (const float*)d_in[9],   // out_w
      (const float*)d_in[13],  // ff1_w
      (const float*)d_in[15],  // ff2_w
      wsH);

  fieldformer_mfma<<<dim3(B), dim3(256), 0, stream>>>(
      (const int*)d_in[0],     // q_lin_idx
      (const int*)d_in[1],     // offsets_ijk
      (const float*)d_in[2],   // coords
      (const float*)d_in[3],   // vals
      (const float*)d_in[4],   // log_gammas
      (const float*)d_in[5],   // proj_w
      (const float*)d_in[6],   // proj_b
      (const float*)d_in[8],   // qkv_b
      (const float*)d_in[10],  // out_b
      (const float*)d_in[11],  // ln1_s
      (const float*)d_in[12],  // ln1_b
      (const float*)d_in[14],  // ff1_b
      (const float*)d_in[16],  // ff2_b
      (const float*)d_in[17],  // ln2_s
      (const float*)d_in[18],  // ln2_b
      (const float*)d_in[19],  // head_ln_s
      (const float*)d_in[20],  // head_ln_b
      (const float*)d_in[21],  // head1_w
      (const float*)d_in[22],  // head1_b
      (const float*)d_in[23],  // head2_w
      (const float*)d_in[24],  // head2_b
      wsH,
      (float*)d_out);
}

// Round 8
// 380.804 us; speedup vs baseline: 1.0059x; 1.0059x over previous
//
#include <hip/hip_runtime.h>
#include <math.h>

#define NXg 128
#define NYg 128
#define NTg 64
#define SEQ 128
#define DIM 64
#define NH 4
#define DHd 16
#define DFFd 128
#define NLAYER 2
#define EPSf 1e-5f

typedef _Float16 f16x8 __attribute__((ext_vector_type(8)));
typedef _Float16 f16x4 __attribute__((ext_vector_type(4)));
typedef __fp16 fp16x2 __attribute__((ext_vector_type(2)));
typedef float f32x4 __attribute__((ext_vector_type(4)));

#define MFMA16(a, b, c) __builtin_amdgcn_mfma_f32_16x16x32_f16(a, b, c, 0, 0, 0)

union FragU { int d[4]; f16x8 v; };
union H4U  { int d[2]; f16x4 v; };
union P2U  { int i; fp16x2 h; };

__device__ __forceinline__ int pk2(float a, float b) {
  P2U u;
  u.h = __builtin_amdgcn_cvt_pkrtz(a, b);
  return u.i;
}
__device__ __forceinline__ float2 up2(int p) {
  P2U u; u.i = p;
  return make_float2((float)u.h[0], (float)u.h[1]);
}

__device__ __forceinline__ f16x8 zero8() {
  f16x8 z;
#pragma unroll
  for (int i = 0; i < 8; ++i) z[i] = (_Float16)0.0f;
  return z;
}
__device__ __forceinline__ f32x4 zero4f() {
  f32x4 z;
  z[0] = 0.f; z[1] = 0.f; z[2] = 0.f; z[3] = 0.f;
  return z;
}
__device__ __forceinline__ f16x8 ld8(const _Float16* p) { return *(const f16x8*)p; }

// Build a K=16 (zero-padded to 32) B-fragment from a C-layout f32x4:
// input d4[jr] = T[dh=quad*4+jr][q=l15]; output B[k=quad*8+j][n=l15].
__device__ __forceinline__ f16x8 frag_k16(f32x4 d4, int quad, int l15) {
  int p0 = pk2(d4[0], d4[1]);
  int p1 = pk2(d4[2], d4[3]);
  int slA = ((2 * quad) * 16 + l15) & 63;
  int slB = ((2 * quad + 1) * 16 + l15) & 63;
  FragU u;
  u.d[0] = __shfl(p0, slA, 64);
  u.d[1] = __shfl(p1, slA, 64);
  u.d[2] = __shfl(p0, slB, 64);
  u.d[3] = __shfl(p1, slB, 64);
  if (quad >= 2) { u.d[0] = 0; u.d[1] = 0; u.d[2] = 0; u.d[3] = 0; }
  return u.v;
}

// Build a K=64 B-fragment (tile kt of 2) from packed register X:
// pk[mt*2+h] = packed pair of X[f=mt*16+quad*4+2h.. +1][q=l15].
__device__ __forceinline__ f16x8 frag_k64(const int pk[8], int kt, int quad, int l15) {
  const int slA = (2 * (quad & 1)) * 16 + l15;
  const int slB = (2 * (quad & 1) + 1) * 16 + l15;
  const bool hi = quad >= 2;  // selects mt = 2kt+1
  int a0 = __shfl(pk[4 * kt + 0], slA, 64), b0 = __shfl(pk[4 * kt + 2], slA, 64);
  int a1 = __shfl(pk[4 * kt + 1], slA, 64), b1 = __shfl(pk[4 * kt + 3], slA, 64);
  int a2 = __shfl(pk[4 * kt + 0], slB, 64), b2 = __shfl(pk[4 * kt + 2], slB, 64);
  int a3 = __shfl(pk[4 * kt + 1], slB, 64), b3 = __shfl(pk[4 * kt + 3], slB, 64);
  FragU u;
  u.d[0] = hi ? b0 : a0;
  u.d[1] = hi ? b1 : a1;
  u.d[2] = hi ? b2 : a2;
  u.d[3] = hi ? b3 : a3;
  return u.v;
}

// residual + LayerNorm on packed register X, one qt tile.
// acc[mt][jr] f32, pkX[8] packed f16 (in/out): [f=mt*16+quad*4+jr][q=l15].
__device__ __forceinline__ void res_ln_qt(const f32x4 acc[4], int pkX[8],
                                          const float* __restrict__ bias,
                                          const float* __restrict__ lns,
                                          const float* __restrict__ lnb,
                                          int quad) {
  float v[4][4];
  float s = 0.f;
#pragma unroll
  for (int mt = 0; mt < 4; ++mt) {
    f32x4 bb = *(const f32x4*)(bias + mt * 16 + quad * 4);
    float2 x0 = up2(pkX[mt * 2 + 0]);
    float2 x1 = up2(pkX[mt * 2 + 1]);
    v[mt][0] = acc[mt][0] + bb[0] + x0.x;
    v[mt][1] = acc[mt][1] + bb[1] + x0.y;
    v[mt][2] = acc[mt][2] + bb[2] + x1.x;
    v[mt][3] = acc[mt][3] + bb[3] + x1.y;
    s += (v[mt][0] + v[mt][1]) + (v[mt][2] + v[mt][3]);
  }
  s += __shfl_xor(s, 16, 64);
  s += __shfl_xor(s, 32, 64);
  const float mu = s * (1.0f / 64.0f);
  float q2 = 0.f;
#pragma unroll
  for (int mt = 0; mt < 4; ++mt)
#pragma unroll
    for (int jr = 0; jr < 4; ++jr) { float d = v[mt][jr] - mu; q2 = fmaf(d, d, q2); }
  q2 += __shfl_xor(q2, 16, 64);
  q2 += __shfl_xor(q2, 32, 64);
  const float rstd = rsqrtf(q2 * (1.0f / 64.0f) + EPSf);
#pragma unroll
  for (int mt = 0; mt < 4; ++mt) {
    f32x4 sv = *(const f32x4*)(lns + mt * 16 + quad * 4);
    f32x4 bv = *(const f32x4*)(lnb + mt * 16 + quad * 4);
    float o0 = fmaf((v[mt][0] - mu) * rstd, sv[0], bv[0]);
    float o1 = fmaf((v[mt][1] - mu) * rstd, sv[1], bv[1]);
    float o2 = fmaf((v[mt][2] - mu) * rstd, sv[2], bv[2]);
    float o3 = fmaf((v[mt][3] - mu) * rstd, sv[3], bv[3]);
    pkX[mt * 2 + 0] = pk2(o0, o1);
    pkX[mt * 2 + 1] = pk2(o2, o3);
  }
}

__global__ void prep_weights(const float* __restrict__ qkv_w,
                             const float* __restrict__ out_w,
                             const float* __restrict__ ff1_w,
                             const float* __restrict__ ff2_w,
                             _Float16* __restrict__ wsH) {
  int i = blockIdx.x * 256 + threadIdx.x;
  if (i < 24576) wsH[i] = (_Float16)qkv_w[i];
  else if (i < 32768) wsH[i] = (_Float16)out_w[i - 24576];
  else if (i < 49152) wsH[i] = (_Float16)ff1_w[i - 32768];
  else if (i < 65536) wsH[i] = (_Float16)ff2_w[i - 49152];
}

// ---------------------------------------------------------------------------
// Fused FieldFormer block: X packed-f16 in registers; K, V, P/FF-hidden in
// LDS (45.3 KB -> 3 blocks/CU). 256 thr = 4 waves per query.
// ---------------------------------------------------------------------------
__global__ __launch_bounds__(256, 3)
void fieldformer_mfma(const int* __restrict__ q_lin_idx,
                      const int* __restrict__ offsets_ijk,
                      const float* __restrict__ coords,
                      const float* __restrict__ vals,
                      const float* __restrict__ log_gammas,
                      const float* __restrict__ proj_w,
                      const float* __restrict__ proj_b,
                      const float* __restrict__ qkv_b,
                      const float* __restrict__ out_b,
                      const float* __restrict__ ln1_s,
                      const float* __restrict__ ln1_b,
                      const float* __restrict__ ff1_b,
                      const float* __restrict__ ff2_b,
                      const float* __restrict__ ln2_s,
                      const float* __restrict__ ln2_b,
                      const float* __restrict__ head_ln_s,
                      const float* __restrict__ head_ln_b,
                      const float* __restrict__ head1_w,
                      const float* __restrict__ head1_b,
                      const float* __restrict__ head2_w,
                      const float* __restrict__ head2_b,
                      const _Float16* __restrict__ wH,
                      float* __restrict__ out) {
  __shared__ __align__(16) _Float16 sPH[128 * 136];  // P / FF-hidden [tok][136]; X staging in phase 0
  __shared__ __align__(16) _Float16 sK[128 * 24];    // K [tok][24]; head scratch at the end
  __shared__ __align__(16) _Float16 sV[16 * 136];    // V^T [dh][136]

  const int tid = threadIdx.x;
  const int wv = tid >> 6;
  const int lane = tid & 63;
  const int quad = lane >> 4;
  const int l15 = lane & 15;
  const int b = blockIdx.x;

  // ---------------- phase 0: tokens -> proj -> sPH staging ----------------
  {
    const int row = tid >> 1, hf = tid & 1;
    const int q = q_lin_idx[b];
    const int qi = q / (NYg * NTg);
    const int qrem = q - qi * (NYg * NTg);
    const int qj = qrem / NTg;
    const int qk = qrem - qj * NTg;
    const int di = offsets_ijk[row * 3 + 0];
    const int dj = offsets_ijk[row * 3 + 1];
    const int dk = offsets_ijk[row * 3 + 2];
    const int I = (qi + di) % NXg;
    const int J = (qj + dj) % NYg;
    int T = qk + dk; T = T < 0 ? 0 : (T > NTg - 1 ? NTg - 1 : T);
    const int nb = I * (NYg * NTg) + J * NTg + T;
    const float qx = coords[q * 3 + 0], qy = coords[q * 3 + 1], qz = coords[q * 3 + 2];
    const float nx_ = coords[nb * 3 + 0], ny_ = coords[nb * 3 + 1], nz_ = coords[nb * 3 + 2];
    float ax = nx_ - qx + 1.0f; ax -= 2.0f * floorf(ax * 0.5f); ax -= 1.0f;
    float ay = ny_ - qy + 1.0f; ay -= 2.0f * floorf(ay * 0.5f); ay -= 1.0f;
    const float at = nz_ - qz;
    float tok[6];
    tok[0] = ax * expf(log_gammas[0]);
    tok[1] = ay * expf(log_gammas[1]);
    tok[2] = at * expf(log_gammas[2]);
    tok[3] = vals[nb * 3 + 0];
    tok[4] = vals[nb * 3 + 1];
    tok[5] = vals[nb * 3 + 2];
#pragma unroll
    for (int ci = 0; ci < 32; ++ci) {
      const int c = hf * 32 + ci;
      const float* w = proj_w + c * 6;
      float a = proj_b[c];
      a = fmaf(tok[0], w[0], a); a = fmaf(tok[1], w[1], a);
      a = fmaf(tok[2], w[2], a); a = fmaf(tok[3], w[3], a);
      a = fmaf(tok[4], w[4], a); a = fmaf(tok[5], w[5], a);
      sPH[row * 136 + c] = (_Float16)a;
    }
  }
  __syncthreads();

  // X packed registers: pkX[qt][mt*2+h] = (X[f],X[f+1]), f=mt*16+quad*4+2h,
  // column q=(wv*2+qt)*16+l15
  int pkX[2][8];
#pragma unroll
  for (int qt = 0; qt < 2; ++qt) {
    const int q = (wv * 2 + qt) * 16 + l15;
#pragma unroll
    for (int mt = 0; mt < 4; ++mt) {
      int2 t = *(const int2*)(sPH + q * 136 + mt * 16 + quad * 4);
      pkX[qt][mt * 2 + 0] = t.x;
      pkX[qt][mt * 2 + 1] = t.y;
    }
  }

  // ---------------- transformer layers ------------------------------------
  for (int l = 0; l < NLAYER; ++l) {
    const _Float16* qkvH = wH + l * 192 * 64;
    const _Float16* woutH = wH + 24576 + l * 64 * 64;
    const _Float16* ff1H = wH + 32768 + l * 128 * 64;
    const _Float16* ff2H = wH + 49152 + l * 64 * 128;
    const float* bqkv = qkv_b + l * 192;

    // X^T B-fragments from packed registers (reused by all heads)
    f16x8 bxf[2][2];
#pragma unroll
    for (int qt = 0; qt < 2; ++qt)
#pragma unroll
      for (int kt = 0; kt < 2; ++kt) bxf[qt][kt] = frag_k64(pkX[qt], kt, quad, l15);

    f32x4 y2[2][4];  // attention out-proj accumulator
#pragma unroll
    for (int qt = 0; qt < 2; ++qt)
#pragma unroll
      for (int mt = 0; mt < 4; ++mt) y2[qt][mt] = zero4f();

    for (int h = 0; h < NH; ++h) {
      // ---- Q^T/K^T/V^T = W * X^T ----
      f32x4 dq[2] = {zero4f(), zero4f()};
      f32x4 dk[2] = {zero4f(), zero4f()};
      f32x4 dv[2] = {zero4f(), zero4f()};
#pragma unroll
      for (int kt = 0; kt < 2; ++kt) {
        f16x8 awq = ld8(qkvH + (h * 16 + l15) * 64 + kt * 32 + quad * 8);
        f16x8 awk = ld8(qkvH + (64 + h * 16 + l15) * 64 + kt * 32 + quad * 8);
        f16x8 awv = ld8(qkvH + (128 + h * 16 + l15) * 64 + kt * 32 + quad * 8);
#pragma unroll
        for (int qt = 0; qt < 2; ++qt) {
          dq[qt] = MFMA16(awq, bxf[qt][kt], dq[qt]);
          dk[qt] = MFMA16(awk, bxf[qt][kt], dk[qt]);
          dv[qt] = MFMA16(awv, bxf[qt][kt], dv[qt]);
        }
      }
      f16x8 bqf[2];
      {
        const f32x4 bq4 = *(const f32x4*)(bqkv + h * 16 + quad * 4);
        const f32x4 bk4 = *(const f32x4*)(bqkv + 64 + h * 16 + quad * 4);
        const f32x4 bv4 = *(const f32x4*)(bqkv + 128 + h * 16 + quad * 4);
#pragma unroll
        for (int qt = 0; qt < 2; ++qt) {
          const int q = (wv * 2 + qt) * 16 + l15;
          H4U k4;
          k4.d[0] = pk2(dk[qt][0] + bk4[0], dk[qt][1] + bk4[1]);
          k4.d[1] = pk2(dk[qt][2] + bk4[2], dk[qt][3] + bk4[3]);
          *(f16x4*)(sK + q * 24 + quad * 4) = k4.v;
#pragma unroll
          for (int jr = 0; jr < 4; ++jr)
            sV[(quad * 4 + jr) * 136 + q] = (_Float16)(dv[qt][jr] + bv4[jr]);
          f32x4 qv;
#pragma unroll
          for (int jr = 0; jr < 4; ++jr) qv[jr] = (dq[qt][jr] + bq4[jr]) * 0.25f;
          bqf[qt] = frag_k16(qv, quad, l15);  // Q stays in registers
        }
      }
      __syncthreads();  // K/V visible to all waves

#pragma unroll
      for (int qt = 0; qt < 2; ++qt) {
        const int q = (wv * 2 + qt) * 16 + l15;
        // scores + shift-free softmax fused per key-tile: only s0 stays live
        float s0 = 0.f;
#pragma unroll
        for (int mt = 0; mt < 8; ++mt) {
          f16x8 ak = (quad < 2) ? ld8(sK + (mt * 16 + l15) * 24 + quad * 8) : zero8();
          f32x4 zc = zero4f();
          f32x4 sc = MFMA16(ak, bqf[qt], zc);
          float e0 = __expf(sc[0]), e1 = __expf(sc[1]);
          float e2 = __expf(sc[2]), e3 = __expf(sc[3]);
          s0 += (e0 + e1) + (e2 + e3);
          H4U pp;
          pp.d[0] = pk2(e0, e1);
          pp.d[1] = pk2(e2, e3);
          *(f16x4*)(sPH + q * 136 + mt * 16 + quad * 4) = pp.v;  // own row
        }
        s0 += __shfl_xor(s0, 16, 64);
        s0 += __shfl_xor(s0, 32, 64);
        const float inv = 1.0f / s0;
        // O^T = V^T * P^T, then normalize by row-sum
        f32x4 ov = zero4f();
#pragma unroll
        for (int kt = 0; kt < 4; ++kt) {
          f16x8 av = ld8(sV + l15 * 136 + kt * 32 + quad * 8);
          f16x8 bp = ld8(sPH + q * 136 + kt * 32 + quad * 8);
          ov = MFMA16(av, bp, ov);
        }
#pragma unroll
        for (int jr = 0; jr < 4; ++jr) ov[jr] *= inv;
        // out-proj partial: Y^T += Wout_h * O_h^T (O frag from registers)
        f16x8 bof = frag_k16(ov, quad, l15);
#pragma unroll
        for (int mt = 0; mt < 4; ++mt) {
          f16x8 aw = (quad < 2) ? ld8(woutH + (mt * 16 + l15) * 64 + h * 16 + quad * 8)
                                : zero8();
          y2[qt][mt] = MFMA16(aw, bof, y2[qt][mt]);
        }
      }
      __syncthreads();  // all sK/sV reads done; next head may overwrite
    }  // heads

    // ---- attention epilogue: bias + residual + LN1 (registers) ----
#pragma unroll
    for (int qt = 0; qt < 2; ++qt)
      res_ln_qt(y2[qt], pkX[qt], out_b + l * 64, ln1_s + l * 64, ln1_b + l * 64, quad);

    // rebuild X fragments post-LN1
#pragma unroll
    for (int qt = 0; qt < 2; ++qt)
#pragma unroll
      for (int kt = 0; kt < 2; ++kt) bxf[qt][kt] = frag_k64(pkX[qt], kt, quad, l15);

    // ---- FF1: H^T = relu(W1 * X^T + b1) -> sPH (own rows) ----
#pragma unroll
    for (int qt = 0; qt < 2; ++qt) {
      const int q = (wv * 2 + qt) * 16 + l15;
      const float* b1 = ff1_b + l * 128;
#pragma unroll
      for (int mt = 0; mt < 8; ++mt) {
        f32x4 f8 = zero4f();
#pragma unroll
        for (int kt = 0; kt < 2; ++kt) {
          f16x8 aw = ld8(ff1H + (mt * 16 + l15) * 64 + kt * 32 + quad * 8);
          f8 = MFMA16(aw, bxf[qt][kt], f8);
        }
        f32x4 bb = *(const f32x4*)(b1 + mt * 16 + quad * 4);
        H4U hh;
        hh.d[0] = pk2(fmaxf(f8[0] + bb[0], 0.f), fmaxf(f8[1] + bb[1], 0.f));
        hh.d[1] = pk2(fmaxf(f8[2] + bb[2], 0.f), fmaxf(f8[3] + bb[3], 0.f));
        *(f16x4*)(sPH + q * 136 + mt * 16 + quad * 4) = hh.v;
      }
    }

    // ---- FF2 + residual + LN2 (registers) ----
#pragma unroll
    for (int qt = 0; qt < 2; ++qt) {
      const int q = (wv * 2 + qt) * 16 + l15;
      f32x4 g4[4];
#pragma unroll
      for (int mt = 0; mt < 4; ++mt) g4[mt] = zero4f();
#pragma unroll
      for (int kt = 0; kt < 4; ++kt) {
        f16x8 bh = ld8(sPH + q * 136 + kt * 32 + quad * 8);
#pragma unroll
        for (int mt = 0; mt < 4; ++mt) {
          f16x8 aw = ld8(ff2H + (mt * 16 + l15) * 128 + kt * 32 + quad * 8);
          g4[mt] = MFMA16(aw, bh, g4[mt]);
        }
      }
      res_ln_qt(g4, pkX[qt], ff2_b + l * 64, ln2_s + l * 64, ln2_b + l * 64, quad);
    }
  }  // layers

  // ---------------- head: mean over S, LN, gelu-MLP -> 3 outputs ----------
  __syncthreads();  // sK free for scratch
  {
    float* pf = (float*)sK;   // 256 partials
    float* gsc = pf + 256;
    float* asc = gsc + 64;
    // column sums from packed register X: in-lane qt, shfl over l15
    f32x4 cs[4];
#pragma unroll
    for (int mt = 0; mt < 4; ++mt) {
      float2 a0 = up2(pkX[0][mt * 2 + 0]), a1 = up2(pkX[0][mt * 2 + 1]);
      float2 b0 = up2(pkX[1][mt * 2 + 0]), b1 = up2(pkX[1][mt * 2 + 1]);
      cs[mt][0] = a0.x + b0.x;
      cs[mt][1] = a0.y + b0.y;
      cs[mt][2] = a1.x + b1.x;
      cs[mt][3] = a1.y + b1.y;
    }
#pragma unroll
    for (int d = 1; d <= 8; d <<= 1)
#pragma unroll
      for (int mt = 0; mt < 4; ++mt)
#pragma unroll
        for (int jr = 0; jr < 4; ++jr) cs[mt][jr] += __shfl_xor(cs[mt][jr], d, 64);
    if (l15 == 0) {
#pragma unroll
      for (int mt = 0; mt < 4; ++mt)
        *(f32x4*)(pf + wv * 64 + mt * 16 + quad * 4) = cs[mt];
    }
    __syncthreads();
    if (tid < 64) {
      const float hm = (pf[tid] + pf[64 + tid] + pf[128 + tid] + pf[192 + tid]) * (1.0f / 128.0f);
      float t = hm;
      t += __shfl_xor(t, 1, 64);  t += __shfl_xor(t, 2, 64);
      t += __shfl_xor(t, 4, 64);  t += __shfl_xor(t, 8, 64);
      t += __shfl_xor(t, 16, 64); t += __shfl_xor(t, 32, 64);
      const float mu = t * (1.0f / 64.0f);
      const float dv = hm - mu;
      float v2 = dv * dv;
      v2 += __shfl_xor(v2, 1, 64);  v2 += __shfl_xor(v2, 2, 64);
      v2 += __shfl_xor(v2, 4, 64);  v2 += __shfl_xor(v2, 8, 64);
      v2 += __shfl_xor(v2, 16, 64); v2 += __shfl_xor(v2, 32, 64);
      const float var = v2 * (1.0f / 64.0f);
      gsc[tid] = fmaf(dv * rsqrtf(var + EPSf), head_ln_s[tid], head_ln_b[tid]);
    }
    __syncthreads();
    if (tid < 64) {
      float z = head1_b[tid];
      for (int k = 0; k < 64; ++k) z = fmaf(gsc[k], head1_w[tid * 64 + k], z);
      asc[tid] = 0.5f * z * (1.0f + erff(z * 0.70710678118654752f));
    }
    __syncthreads();
    if (tid < 3) {
      float z = head2_b[tid];
      for (int k = 0; k < 64; ++k) z = fmaf(asc[k], head2_w[tid * 64 + k], z);
      out[b * 3 + tid] = z;
    }
  }
}

extern "C" void kernel_launch(void* const* d_in, const int* in_sizes, int n_in,
                              void* d_out, int out_size, void* d_ws, size_t ws_size,
                              hipStream_t stream) {
  (void)n_in; (void)ws_size; (void)out_size;
  const int B = in_sizes[0];
  _Float16* wsH = (_Float16*)d_ws;  // 65536 halves = 128 KB

  prep_weights<<<dim3(256), dim3(256), 0, stream>>>(
      (const float*)d_in[7],   // qkv_w
      (const float*)d_in[9],   // out_w
      (const float*)d_in[13],  // ff1_w
      (const float*)d_in[15],  // ff2_w
      wsH);

  fieldformer_mfma<<<dim3(B), dim3(256), 0, stream>>>(
      (const int*)d_in[0],     // q_lin_idx
      (const int*)d_in[1],     // offsets_ijk
      (const float*)d_in[2],   // coords
      (const float*)d_in[3],   // vals
      (const float*)d_in[4],   // log_gammas
      (const float*)d_in[5],   // proj_w
      (const float*)d_in[6],   // proj_b
      (const float*)d_in[8],   // qkv_b
      (const float*)d_in[10],  // out_b
      (const float*)d_in[11],  // ln1_s
      (const float*)d_in[12],  // ln1_b
      (const float*)d_in[14],  // ff1_b
      (const float*)d_in[16],  // ff2_b
      (const float*)d_in[17],  // ln2_s
      (const float*)d_in[18],  // ln2_b
      (const float*)d_in[19],  // head_ln_s
      (const float*)d_in[20],  // head_ln_b
      (const float*)d_in[21],  // head1_w
      (const float*)d_in[22],  // head1_b
      (const float*)d_in[23],  // head2_w
      (const float*)d_in[24],  // head2_b
      wsH,
      (float*)d_out);
}

// Round 9
// 342.673 us; speedup vs baseline: 1.1178x; 1.1113x over previous
//
#include <hip/hip_runtime.h>
#include <math.h>

#define NXg 128
#define NYg 128
#define NTg 64
#define SEQ 128
#define DIM 64
#define NH 4
#define DHd 16
#define DFFd 128
#define NLAYER 2
#define EPSf 1e-5f

typedef _Float16 f16x8 __attribute__((ext_vector_type(8)));
typedef _Float16 f16x4 __attribute__((ext_vector_type(4)));
typedef __fp16 fp16x2 __attribute__((ext_vector_type(2)));
typedef float f32x4 __attribute__((ext_vector_type(4)));

#define MFMA16(a, b, c) __builtin_amdgcn_mfma_f32_16x16x32_f16(a, b, c, 0, 0, 0)

union FragU { int d[4]; f16x8 v; };
union H4U  { int d[2]; f16x4 v; };
union P2U  { int i; fp16x2 h; };

__device__ __forceinline__ int pk2(float a, float b) {
  P2U u;
  u.h = __builtin_amdgcn_cvt_pkrtz(a, b);
  return u.i;
}
__device__ __forceinline__ float2 up2(int p) {
  P2U u; u.i = p;
  return make_float2((float)u.h[0], (float)u.h[1]);
}

__device__ __forceinline__ f16x8 zero8() {
  f16x8 z;
#pragma unroll
  for (int i = 0; i < 8; ++i) z[i] = (_Float16)0.0f;
  return z;
}
__device__ __forceinline__ f32x4 zero4f() {
  f32x4 z;
  z[0] = 0.f; z[1] = 0.f; z[2] = 0.f; z[3] = 0.f;
  return z;
}
__device__ __forceinline__ f16x8 ld8(const _Float16* p) { return *(const f16x8*)p; }

// K=16 (zero-padded to 32) B-fragment from packed C-layout pairs:
// p0=(T[q0],T[q1]), p1=(T[q2],T[q3]) at dh=quad*4+jr, col q=l15.
// Output B[k=quad*8+j][n=l15]; quads>=2 zero.
__device__ __forceinline__ f16x8 frag_k16p(int p0, int p1, int quad, int l15) {
  int slA = ((2 * quad) * 16 + l15) & 63;
  int slB = ((2 * quad + 1) * 16 + l15) & 63;
  FragU u;
  u.d[0] = __shfl(p0, slA, 64);
  u.d[1] = __shfl(p1, slA, 64);
  u.d[2] = __shfl(p0, slB, 64);
  u.d[3] = __shfl(p1, slB, 64);
  if (quad >= 2) { u.d[0] = 0; u.d[1] = 0; u.d[2] = 0; u.d[3] = 0; }
  return u.v;
}

// K=64 B-fragment (tile kt of 2) from packed register tensor:
// pk[mt*2+h] = packed pair of T[f=mt*16+quad*4+2h..+1][col=l15], mt in [0,4).
__device__ __forceinline__ f16x8 frag_k64(const int* pk, int kt, int quad, int l15) {
  const int slA = (2 * (quad & 1)) * 16 + l15;
  const int slB = (2 * (quad & 1) + 1) * 16 + l15;
  const bool hi = quad >= 2;  // selects mt = 2kt+1
  int a0 = __shfl(pk[4 * kt + 0], slA, 64), b0 = __shfl(pk[4 * kt + 2], slA, 64);
  int a1 = __shfl(pk[4 * kt + 1], slA, 64), b1 = __shfl(pk[4 * kt + 3], slA, 64);
  int a2 = __shfl(pk[4 * kt + 0], slB, 64), b2 = __shfl(pk[4 * kt + 2], slB, 64);
  int a3 = __shfl(pk[4 * kt + 1], slB, 64), b3 = __shfl(pk[4 * kt + 3], slB, 64);
  FragU u;
  u.d[0] = hi ? b0 : a0;
  u.d[1] = hi ? b1 : a1;
  u.d[2] = hi ? b2 : a2;
  u.d[3] = hi ? b3 : a3;
  return u.v;
}

// residual + LayerNorm on packed register X, one qt tile.
__device__ __forceinline__ void res_ln_qt(const f32x4 acc[4], int pkX[8],
                                          const float* __restrict__ bias,
                                          const float* __restrict__ lns,
                                          const float* __restrict__ lnb,
                                          int quad) {
  float v[4][4];
  float s = 0.f;
#pragma unroll
  for (int mt = 0; mt < 4; ++mt) {
    f32x4 bb = *(const f32x4*)(bias + mt * 16 + quad * 4);
    float2 x0 = up2(pkX[mt * 2 + 0]);
    float2 x1 = up2(pkX[mt * 2 + 1]);
    v[mt][0] = acc[mt][0] + bb[0] + x0.x;
    v[mt][1] = acc[mt][1] + bb[1] + x0.y;
    v[mt][2] = acc[mt][2] + bb[2] + x1.x;
    v[mt][3] = acc[mt][3] + bb[3] + x1.y;
    s += (v[mt][0] + v[mt][1]) + (v[mt][2] + v[mt][3]);
  }
  s += __shfl_xor(s, 16, 64);
  s += __shfl_xor(s, 32, 64);
  const float mu = s * (1.0f / 64.0f);
  float q2 = 0.f;
#pragma unroll
  for (int mt = 0; mt < 4; ++mt)
#pragma unroll
    for (int jr = 0; jr < 4; ++jr) { float d = v[mt][jr] - mu; q2 = fmaf(d, d, q2); }
  q2 += __shfl_xor(q2, 16, 64);
  q2 += __shfl_xor(q2, 32, 64);
  const float rstd = rsqrtf(q2 * (1.0f / 64.0f) + EPSf);
#pragma unroll
  for (int mt = 0; mt < 4; ++mt) {
    f32x4 sv = *(const f32x4*)(lns + mt * 16 + quad * 4);
    f32x4 bv = *(const f32x4*)(lnb + mt * 16 + quad * 4);
    float o0 = fmaf((v[mt][0] - mu) * rstd, sv[0], bv[0]);
    float o1 = fmaf((v[mt][1] - mu) * rstd, sv[1], bv[1]);
    float o2 = fmaf((v[mt][2] - mu) * rstd, sv[2], bv[2]);
    float o3 = fmaf((v[mt][3] - mu) * rstd, sv[3], bv[3]);
    pkX[mt * 2 + 0] = pk2(o0, o1);
    pkX[mt * 2 + 1] = pk2(o2, o3);
  }
}

__global__ void prep_weights(const float* __restrict__ qkv_w,
                             const float* __restrict__ out_w,
                             const float* __restrict__ ff1_w,
                             const float* __restrict__ ff2_w,
                             _Float16* __restrict__ wsH) {
  int i = blockIdx.x * 256 + threadIdx.x;
  if (i < 24576) wsH[i] = (_Float16)qkv_w[i];
  else if (i < 32768) wsH[i] = (_Float16)out_w[i - 24576];
  else if (i < 49152) wsH[i] = (_Float16)ff1_w[i - 32768];
  else if (i < 65536) wsH[i] = (_Float16)ff2_w[i - 49152];
}

// ---------------------------------------------------------------------------
// Fused FieldFormer block, 2 barriers/layer: all-head K/V staged to LDS once;
// X, Q, P, O, FF-hidden all live in registers (shuffle-built MFMA fragments).
// LDS 35.8 KB. 256 thr = 4 waves per query, __launch_bounds__(256,2): no spills.
// ---------------------------------------------------------------------------
__global__ __launch_bounds__(256, 2)
void fieldformer_mfma(const int* __restrict__ q_lin_idx,
                      const int* __restrict__ offsets_ijk,
                      const float* __restrict__ coords,
                      const float* __restrict__ vals,
                      const float* __restrict__ log_gammas,
                      const float* __restrict__ proj_w,
                      const float* __restrict__ proj_b,
                      const float* __restrict__ qkv_b,
                      const float* __restrict__ out_b,
                      const float* __restrict__ ln1_s,
                      const float* __restrict__ ln1_b,
                      const float* __restrict__ ff1_b,
                      const float* __restrict__ ff2_b,
                      const float* __restrict__ ln2_s,
                      const float* __restrict__ ln2_b,
                      const float* __restrict__ head_ln_s,
                      const float* __restrict__ head_ln_b,
                      const float* __restrict__ head1_w,
                      const float* __restrict__ head1_b,
                      const float* __restrict__ head2_w,
                      const float* __restrict__ head2_b,
                      const _Float16* __restrict__ wH,
                      float* __restrict__ out) {
  __shared__ __align__(16) _Float16 sK[128 * 72];  // K all heads [tok][72]; X staging; head scratch
  __shared__ __align__(16) _Float16 sV[64 * 136];  // V^T all heads [dh][136]

  const int tid = threadIdx.x;
  const int wv = tid >> 6;
  const int lane = tid & 63;
  const int quad = lane >> 4;
  const int l15 = lane & 15;
  const int b = blockIdx.x;

  // ---------------- phase 0: tokens -> proj -> sK staging -----------------
  {
    const int row = tid >> 1, hf = tid & 1;
    const int q = q_lin_idx[b];
    const int qi = q / (NYg * NTg);
    const int qrem = q - qi * (NYg * NTg);
    const int qj = qrem / NTg;
    const int qk = qrem - qj * NTg;
    const int di = offsets_ijk[row * 3 + 0];
    const int dj = offsets_ijk[row * 3 + 1];
    const int dk = offsets_ijk[row * 3 + 2];
    const int I = (qi + di) % NXg;
    const int J = (qj + dj) % NYg;
    int T = qk + dk; T = T < 0 ? 0 : (T > NTg - 1 ? NTg - 1 : T);
    const int nb = I * (NYg * NTg) + J * NTg + T;
    const float qx = coords[q * 3 + 0], qy = coords[q * 3 + 1], qz = coords[q * 3 + 2];
    const float nx_ = coords[nb * 3 + 0], ny_ = coords[nb * 3 + 1], nz_ = coords[nb * 3 + 2];
    float ax = nx_ - qx + 1.0f; ax -= 2.0f * floorf(ax * 0.5f); ax -= 1.0f;
    float ay = ny_ - qy + 1.0f; ay -= 2.0f * floorf(ay * 0.5f); ay -= 1.0f;
    const float at = nz_ - qz;
    float tok[6];
    tok[0] = ax * expf(log_gammas[0]);
    tok[1] = ay * expf(log_gammas[1]);
    tok[2] = at * expf(log_gammas[2]);
    tok[3] = vals[nb * 3 + 0];
    tok[4] = vals[nb * 3 + 1];
    tok[5] = vals[nb * 3 + 2];
#pragma unroll
    for (int ci = 0; ci < 32; ++ci) {
      const int c = hf * 32 + ci;
      const float* w = proj_w + c * 6;
      float a = proj_b[c];
      a = fmaf(tok[0], w[0], a); a = fmaf(tok[1], w[1], a);
      a = fmaf(tok[2], w[2], a); a = fmaf(tok[3], w[3], a);
      a = fmaf(tok[4], w[4], a); a = fmaf(tok[5], w[5], a);
      sK[row * 72 + c] = (_Float16)a;
    }
  }
  __syncthreads();

  // X packed registers: pkX[qt][mt*2+h] = (X[f],X[f+1]), f=mt*16+quad*4+2h,
  // column q=(wv*2+qt)*16+l15
  int pkX[2][8];
#pragma unroll
  for (int qt = 0; qt < 2; ++qt) {
    const int q = (wv * 2 + qt) * 16 + l15;
#pragma unroll
    for (int mt = 0; mt < 4; ++mt) {
      int2 t = *(const int2*)(sK + q * 72 + mt * 16 + quad * 4);
      pkX[qt][mt * 2 + 0] = t.x;
      pkX[qt][mt * 2 + 1] = t.y;
    }
  }

  // ---------------- transformer layers ------------------------------------
  for (int l = 0; l < NLAYER; ++l) {
    const _Float16* qkvH = wH + l * 192 * 64;
    const _Float16* woutH = wH + 24576 + l * 64 * 64;
    const _Float16* ff1H = wH + 32768 + l * 128 * 64;
    const _Float16* ff2H = wH + 49152 + l * 64 * 128;
    const float* bqkv = qkv_b + l * 192;

    __syncthreads();  // barrier 1: previous consumers of sK/sV done

    // X^T B-fragments from packed registers
    f16x8 bxf[2][2];
#pragma unroll
    for (int qt = 0; qt < 2; ++qt)
#pragma unroll
      for (int kt = 0; kt < 2; ++kt) bxf[qt][kt] = frag_k64(pkX[qt], kt, quad, l15);

    // ---- all-head QKV staging: K,V -> LDS; Q packed in registers ----
    int pkQ[2][8];
#pragma unroll
    for (int hd = 0; hd < NH; ++hd) {
      f32x4 dq[2] = {zero4f(), zero4f()};
      f32x4 dk[2] = {zero4f(), zero4f()};
      f32x4 dv[2] = {zero4f(), zero4f()};
#pragma unroll
      for (int kt = 0; kt < 2; ++kt) {
        f16x8 awq = ld8(qkvH + (hd * 16 + l15) * 64 + kt * 32 + quad * 8);
        f16x8 awk = ld8(qkvH + (64 + hd * 16 + l15) * 64 + kt * 32 + quad * 8);
        f16x8 awv = ld8(qkvH + (128 + hd * 16 + l15) * 64 + kt * 32 + quad * 8);
#pragma unroll
        for (int qt = 0; qt < 2; ++qt) {
          dq[qt] = MFMA16(awq, bxf[qt][kt], dq[qt]);
          dk[qt] = MFMA16(awk, bxf[qt][kt], dk[qt]);
          dv[qt] = MFMA16(awv, bxf[qt][kt], dv[qt]);
        }
      }
      const f32x4 bq4 = *(const f32x4*)(bqkv + hd * 16 + quad * 4);
      const f32x4 bk4 = *(const f32x4*)(bqkv + 64 + hd * 16 + quad * 4);
      const f32x4 bv4 = *(const f32x4*)(bqkv + 128 + hd * 16 + quad * 4);
#pragma unroll
      for (int qt = 0; qt < 2; ++qt) {
        const int q = (wv * 2 + qt) * 16 + l15;
        H4U k4;
        k4.d[0] = pk2(dk[qt][0] + bk4[0], dk[qt][1] + bk4[1]);
        k4.d[1] = pk2(dk[qt][2] + bk4[2], dk[qt][3] + bk4[3]);
        *(f16x4*)(sK + q * 72 + hd * 16 + quad * 4) = k4.v;
#pragma unroll
        for (int jr = 0; jr < 4; ++jr)
          sV[(hd * 16 + quad * 4 + jr) * 136 + q] = (_Float16)(dv[qt][jr] + bv4[jr]);
        pkQ[qt][hd * 2 + 0] = pk2((dq[qt][0] + bq4[0]) * 0.25f, (dq[qt][1] + bq4[1]) * 0.25f);
        pkQ[qt][hd * 2 + 1] = pk2((dq[qt][2] + bq4[2]) * 0.25f, (dq[qt][3] + bq4[3]) * 0.25f);
      }
    }
    __syncthreads();  // barrier 2: K/V visible; attention below is barrier-free

    // ---- attention: scores -> softmax -> PV -> pack O (all registers) ----
    int pkO[2][8];
#pragma unroll
    for (int hd = 0; hd < NH; ++hd) {
#pragma unroll
      for (int qt = 0; qt < 2; ++qt) {
        f16x8 bqf = frag_k16p(pkQ[qt][hd * 2 + 0], pkQ[qt][hd * 2 + 1], quad, l15);
        float s0 = 0.f;
        int pkP[16];
#pragma unroll
        for (int mt = 0; mt < 8; ++mt) {
          f16x8 ak = (quad < 2) ? ld8(sK + (mt * 16 + l15) * 72 + hd * 16 + quad * 8)
                                : zero8();
          f32x4 zc = zero4f();
          f32x4 sc = MFMA16(ak, bqf, zc);
          float e0 = __expf(sc[0]), e1 = __expf(sc[1]);
          float e2 = __expf(sc[2]), e3 = __expf(sc[3]);
          s0 += (e0 + e1) + (e2 + e3);
          pkP[mt * 2 + 0] = pk2(e0, e1);
          pkP[mt * 2 + 1] = pk2(e2, e3);
        }
        s0 += __shfl_xor(s0, 16, 64);
        s0 += __shfl_xor(s0, 32, 64);
        const float inv = 1.0f / s0;
        // PV: O^T = V^T * P^T (K=128), P fragments from registers
        f32x4 ov = zero4f();
#pragma unroll
        for (int kt2 = 0; kt2 < 4; ++kt2) {
          f16x8 av = ld8(sV + (hd * 16 + l15) * 136 + kt2 * 32 + quad * 8);
          f16x8 bp = frag_k64(pkP + 8 * (kt2 >> 1), kt2 & 1, quad, l15);
          ov = MFMA16(av, bp, ov);
        }
        pkO[qt][hd * 2 + 0] = pk2(ov[0] * inv, ov[1] * inv);
        pkO[qt][hd * 2 + 1] = pk2(ov[2] * inv, ov[3] * inv);
      }
    }

    // ---- out-proj (K=64 full GEMM) + residual + LN1 (registers) ----
#pragma unroll
    for (int qt = 0; qt < 2; ++qt) {
      f32x4 y2[4] = {zero4f(), zero4f(), zero4f(), zero4f()};
#pragma unroll
      for (int kt = 0; kt < 2; ++kt) {
        f16x8 bof = frag_k64(pkO[qt], kt, quad, l15);
#pragma unroll
        for (int mt = 0; mt < 4; ++mt) {
          f16x8 aw = ld8(woutH + (mt * 16 + l15) * 64 + kt * 32 + quad * 8);
          y2[mt] = MFMA16(aw, bof, y2[mt]);
        }
      }
      res_ln_qt(y2, pkX[qt], out_b + l * 64, ln1_s + l * 64, ln1_b + l * 64, quad);
    }

    // ---- FF (all registers): H = relu(W1 X + b1); X = LN2(X + W2 H + b2) --
#pragma unroll
    for (int qt = 0; qt < 2; ++qt) {
      f16x8 bx2[2];
#pragma unroll
      for (int kt = 0; kt < 2; ++kt) bx2[kt] = frag_k64(pkX[qt], kt, quad, l15);
      const float* b1 = ff1_b + l * 128;
      int pkH[16];
#pragma unroll
      for (int mt = 0; mt < 8; ++mt) {
        f32x4 f8 = zero4f();
#pragma unroll
        for (int kt = 0; kt < 2; ++kt) {
          f16x8 aw = ld8(ff1H + (mt * 16 + l15) * 64 + kt * 32 + quad * 8);
          f8 = MFMA16(aw, bx2[kt], f8);
        }
        f32x4 bb = *(const f32x4*)(b1 + mt * 16 + quad * 4);
        pkH[mt * 2 + 0] = pk2(fmaxf(f8[0] + bb[0], 0.f), fmaxf(f8[1] + bb[1], 0.f));
        pkH[mt * 2 + 1] = pk2(fmaxf(f8[2] + bb[2], 0.f), fmaxf(f8[3] + bb[3], 0.f));
      }
      f32x4 g4[4] = {zero4f(), zero4f(), zero4f(), zero4f()};
#pragma unroll
      for (int kt = 0; kt < 4; ++kt) {
        f16x8 bh = frag_k64(pkH + 8 * (kt >> 1), kt & 1, quad, l15);
#pragma unroll
        for (int mt = 0; mt < 4; ++mt) {
          f16x8 aw = ld8(ff2H + (mt * 16 + l15) * 128 + kt * 32 + quad * 8);
          g4[mt] = MFMA16(aw, bh, g4[mt]);
        }
      }
      res_ln_qt(g4, pkX[qt], ff2_b + l * 64, ln2_s + l * 64, ln2_b + l * 64, quad);
    }
  }  // layers

  // ---------------- head: mean over S, LN, gelu-MLP -> 3 outputs ----------
  __syncthreads();  // sK free for scratch
  {
    float* pf = (float*)sK;   // 256 partials
    float* gsc = pf + 256;
    float* asc = gsc + 64;
    // column sums from packed register X: in-lane qt, shfl over l15
    f32x4 cs[4];
#pragma unroll
    for (int mt = 0; mt < 4; ++mt) {
      float2 a0 = up2(pkX[0][mt * 2 + 0]), a1 = up2(pkX[0][mt * 2 + 1]);
      float2 b0 = up2(pkX[1][mt * 2 + 0]), b1 = up2(pkX[1][mt * 2 + 1]);
      cs[mt][0] = a0.x + b0.x;
      cs[mt][1] = a0.y + b0.y;
      cs[mt][2] = a1.x + b1.x;
      cs[mt][3] = a1.y + b1.y;
    }
#pragma unroll
    for (int d = 1; d <= 8; d <<= 1)
#pragma unroll
      for (int mt = 0; mt < 4; ++mt)
#pragma unroll
        for (int jr = 0; jr < 4; ++jr) cs[mt][jr] += __shfl_xor(cs[mt][jr], d, 64);
    if (l15 == 0) {
#pragma unroll
      for (int mt = 0; mt < 4; ++mt)
        *(f32x4*)(pf + wv * 64 + mt * 16 + quad * 4) = cs[mt];
    }
    __syncthreads();
    if (tid < 64) {
      const float hm = (pf[tid] + pf[64 + tid] + pf[128 + tid] + pf[192 + tid]) * (1.0f / 128.0f);
      float t = hm;
      t += __shfl_xor(t, 1, 64);  t += __shfl_xor(t, 2, 64);
      t += __shfl_xor(t, 4, 64);  t += __shfl_xor(t, 8, 64);
      t += __shfl_xor(t, 16, 64); t += __shfl_xor(t, 32, 64);
      const float mu = t * (1.0f / 64.0f);
      const float dv = hm - mu;
      float v2 = dv * dv;
      v2 += __shfl_xor(v2, 1, 64);  v2 += __shfl_xor(v2, 2, 64);
      v2 += __shfl_xor(v2, 4, 64);  v2 += __shfl_xor(v2, 8, 64);
      v2 += __shfl_xor(v2, 16, 64); v2 += __shfl_xor(v2, 32, 64);
      const float var = v2 * (1.0f / 64.0f);
      gsc[tid] = fmaf(dv * rsqrtf(var + EPSf), head_ln_s[tid], head_ln_b[tid]);
    }
    __syncthreads();
    if (tid < 64) {
      float z = head1_b[tid];
      for (int k = 0; k < 64; ++k) z = fmaf(gsc[k], head1_w[tid * 64 + k], z);
      asc[tid] = 0.5f * z * (1.0f + erff(z * 0.70710678118654752f));
    }
    __syncthreads();
    if (tid < 3) {
      float z = head2_b[tid];
      for (int k = 0; k < 64; ++k) z = fmaf(asc[k], head2_w[tid * 64 + k], z);
      out[b * 3 + tid] = z;
    }
  }
}

extern "C" void kernel_launch(void* const* d_in, const int* in_sizes, int n_in,
                              void* d_out, int out_size, void* d_ws, size_t ws_size,
                              hipStream_t stream) {
  (void)n_in; (void)ws_size; (void)out_size;
  const int B = in_sizes[0];
  _Float16* wsH = (_Float16*)d_ws;  // 65536 halves = 128 KB

  prep_weights<<<dim3(256), dim3(256), 0, stream>>>(
      (const float*)d_in[7],   // qkv_w
      (const float*)d_in[9],   // out_w
      (const float*)d_in[13],  // ff1_w
      (const float*)d_in[15],  // ff2_w
      wsH);

  fieldformer_mfma<<<dim3(B), dim3(256), 0, stream>>>(
      (const int*)d_in[0],     // q_lin_idx
      (const int*)d_in[1],     // offsets_ijk
      (const float*)d_in[2],   // coords
      (const float*)d_in[3],   // vals
      (const float*)d_in[4],   // log_gammas
      (const float*)d_in[5],   // proj_w
      (const float*)d_in[6],   // proj_b
      (const float*)d_in[8],   // qkv_b
      (const float*)d_in[10],  // out_b
      (const float*)d_in[11],  // ln1_s
      (const float*)d_in[12],  // ln1_b
      (const float*)d_in[14],  // ff1_b
      (const float*)d_in[16],  // ff2_b
      (const float*)d_in[17],  // ln2_s
      (const float*)d_in[18],  // ln2_b
      (const float*)d_in[19],  // head_ln_s
      (const float*)d_in[20],  // head_ln_b
      (const float*)d_in[21],  // head1_w
      (const float*)d_in[22],  // head1_b
      (const float*)d_in[23],  // head2_w
      (const float*)d_in[24],  // head2_b
      wsH,
      (float*)d_out);
}

// Round 10
// 319.737 us; speedup vs baseline: 1.1980x; 1.0717x over previous
//
#include <hip/hip_runtime.h>
#include <math.h>

#define NXg 128
#define NYg 128
#define NTg 64
#define SEQ 128
#define DIM 64
#define NH 4
#define DHd 16
#define DFFd 128
#define NLAYER 2
#define EPSf 1e-5f

typedef _Float16 f16x8 __attribute__((ext_vector_type(8)));
typedef _Float16 f16x4 __attribute__((ext_vector_type(4)));
typedef __fp16 fp16x2 __attribute__((ext_vector_type(2)));
typedef float f32x4 __attribute__((ext_vector_type(4)));

#define MFMA16(a, b, c) __builtin_amdgcn_mfma_f32_16x16x32_f16(a, b, c, 0, 0, 0)

union FragU { int d[4]; f16x8 v; };
union H4U  { int d[2]; f16x4 v; };
union P2U  { int i; fp16x2 h; };

__device__ __forceinline__ int pk2(float a, float b) {
  P2U u;
  u.h = __builtin_amdgcn_cvt_pkrtz(a, b);
  return u.i;
}
__device__ __forceinline__ float2 up2(int p) {
  P2U u; u.i = p;
  return make_float2((float)u.h[0], (float)u.h[1]);
}

__device__ __forceinline__ f16x8 zero8() {
  f16x8 z;
#pragma unroll
  for (int i = 0; i < 8; ++i) z[i] = (_Float16)0.0f;
  return z;
}
__device__ __forceinline__ f32x4 zero4f() {
  f32x4 z;
  z[0] = 0.f; z[1] = 0.f; z[2] = 0.f; z[3] = 0.f;
  return z;
}
__device__ __forceinline__ f16x8 ld8(const _Float16* p) { return *(const f16x8*)p; }

// K=16 (zero-padded to 32) B-fragment from packed C-layout pairs:
// p0=(T[q0],T[q1]), p1=(T[q2],T[q3]) at dh=quad*4+jr, col q=l15.
// Output B[k=quad*8+j][n=l15]; quads>=2 zero.
__device__ __forceinline__ f16x8 frag_k16p(int p0, int p1, int quad, int l15) {
  int slA = ((2 * quad) * 16 + l15) & 63;
  int slB = ((2 * quad + 1) * 16 + l15) & 63;
  FragU u;
  u.d[0] = __shfl(p0, slA, 64);
  u.d[1] = __shfl(p1, slA, 64);
  u.d[2] = __shfl(p0, slB, 64);
  u.d[3] = __shfl(p1, slB, 64);
  if (quad >= 2) { u.d[0] = 0; u.d[1] = 0; u.d[2] = 0; u.d[3] = 0; }
  return u.v;
}

// K=64 B-fragment (tile kt of 2) from packed register tensor:
// pk[mt*2+h] = packed pair of T[f=mt*16+quad*4+2h..+1][col=l15], mt in [0,4).
__device__ __forceinline__ f16x8 frag_k64(const int* pk, int kt, int quad, int l15) {
  const int slA = (2 * (quad & 1)) * 16 + l15;
  const int slB = (2 * (quad & 1) + 1) * 16 + l15;
  const bool hi = quad >= 2;  // selects mt = 2kt+1
  int a0 = __shfl(pk[4 * kt + 0], slA, 64), b0 = __shfl(pk[4 * kt + 2], slA, 64);
  int a1 = __shfl(pk[4 * kt + 1], slA, 64), b1 = __shfl(pk[4 * kt + 3], slA, 64);
  int a2 = __shfl(pk[4 * kt + 0], slB, 64), b2 = __shfl(pk[4 * kt + 2], slB, 64);
  int a3 = __shfl(pk[4 * kt + 1], slB, 64), b3 = __shfl(pk[4 * kt + 3], slB, 64);
  FragU u;
  u.d[0] = hi ? b0 : a0;
  u.d[1] = hi ? b1 : a1;
  u.d[2] = hi ? b2 : a2;
  u.d[3] = hi ? b3 : a3;
  return u.v;
}

// residual + LayerNorm on packed register X, one qt tile.
__device__ __forceinline__ void res_ln_qt(const f32x4 acc[4], int pkX[8],
                                          const float* __restrict__ bias,
                                          const float* __restrict__ lns,
                                          const float* __restrict__ lnb,
                                          int quad) {
  float v[4][4];
  float s = 0.f;
#pragma unroll
  for (int mt = 0; mt < 4; ++mt) {
    f32x4 bb = *(const f32x4*)(bias + mt * 16 + quad * 4);
    float2 x0 = up2(pkX[mt * 2 + 0]);
    float2 x1 = up2(pkX[mt * 2 + 1]);
    v[mt][0] = acc[mt][0] + bb[0] + x0.x;
    v[mt][1] = acc[mt][1] + bb[1] + x0.y;
    v[mt][2] = acc[mt][2] + bb[2] + x1.x;
    v[mt][3] = acc[mt][3] + bb[3] + x1.y;
    s += (v[mt][0] + v[mt][1]) + (v[mt][2] + v[mt][3]);
  }
  s += __shfl_xor(s, 16, 64);
  s += __shfl_xor(s, 32, 64);
  const float mu = s * (1.0f / 64.0f);
  float q2 = 0.f;
#pragma unroll
  for (int mt = 0; mt < 4; ++mt)
#pragma unroll
    for (int jr = 0; jr < 4; ++jr) { float d = v[mt][jr] - mu; q2 = fmaf(d, d, q2); }
  q2 += __shfl_xor(q2, 16, 64);
  q2 += __shfl_xor(q2, 32, 64);
  const float rstd = rsqrtf(q2 * (1.0f / 64.0f) + EPSf);
#pragma unroll
  for (int mt = 0; mt < 4; ++mt) {
    f32x4 sv = *(const f32x4*)(lns + mt * 16 + quad * 4);
    f32x4 bv = *(const f32x4*)(lnb + mt * 16 + quad * 4);
    float o0 = fmaf((v[mt][0] - mu) * rstd, sv[0], bv[0]);
    float o1 = fmaf((v[mt][1] - mu) * rstd, sv[1], bv[1]);
    float o2 = fmaf((v[mt][2] - mu) * rstd, sv[2], bv[2]);
    float o3 = fmaf((v[mt][3] - mu) * rstd, sv[3], bv[3]);
    pkX[mt * 2 + 0] = pk2(o0, o1);
    pkX[mt * 2 + 1] = pk2(o2, o3);
  }
}

__global__ void prep_weights(const float* __restrict__ qkv_w,
                             const float* __restrict__ out_w,
                             const float* __restrict__ ff1_w,
                             const float* __restrict__ ff2_w,
                             _Float16* __restrict__ wsH) {
  int i = blockIdx.x * 256 + threadIdx.x;
  if (i < 24576) wsH[i] = (_Float16)qkv_w[i];
  else if (i < 32768) wsH[i] = (_Float16)out_w[i - 24576];
  else if (i < 49152) wsH[i] = (_Float16)ff1_w[i - 32768];
  else if (i < 65536) wsH[i] = (_Float16)ff2_w[i - 49152];
}

// ---------------------------------------------------------------------------
// Fused FieldFormer block, 2 barriers/layer; scores->softmax->PV and FF1->FF2
// stream-fused (minimal live registers, MFMA chains interleaved).
// LDS 35.8 KB; __launch_bounds__(256,3) targets 3 blocks/CU without spills.
// ---------------------------------------------------------------------------
__global__ __launch_bounds__(256, 3)
void fieldformer_mfma(const int* __restrict__ q_lin_idx,
                      const int* __restrict__ offsets_ijk,
                      const float* __restrict__ coords,
                      const float* __restrict__ vals,
                      const float* __restrict__ log_gammas,
                      const float* __restrict__ proj_w,
                      const float* __restrict__ proj_b,
                      const float* __restrict__ qkv_b,
                      const float* __restrict__ out_b,
                      const float* __restrict__ ln1_s,
                      const float* __restrict__ ln1_b,
                      const float* __restrict__ ff1_b,
                      const float* __restrict__ ff2_b,
                      const float* __restrict__ ln2_s,
                      const float* __restrict__ ln2_b,
                      const float* __restrict__ head_ln_s,
                      const float* __restrict__ head_ln_b,
                      const float* __restrict__ head1_w,
                      const float* __restrict__ head1_b,
                      const float* __restrict__ head2_w,
                      const float* __restrict__ head2_b,
                      const _Float16* __restrict__ wH,
                      float* __restrict__ out) {
  __shared__ __align__(16) _Float16 sK[128 * 72];  // K all heads [tok][72]; X staging; head scratch
  __shared__ __align__(16) _Float16 sV[64 * 136];  // V^T all heads [dh][136]

  const int tid = threadIdx.x;
  const int wv = tid >> 6;
  const int lane = tid & 63;
  const int quad = lane >> 4;
  const int l15 = lane & 15;
  const int b = blockIdx.x;

  // ---------------- phase 0: tokens -> proj -> sK staging -----------------
  {
    const int row = tid >> 1, hf = tid & 1;
    const int q = q_lin_idx[b];
    const int qi = q / (NYg * NTg);
    const int qrem = q - qi * (NYg * NTg);
    const int qj = qrem / NTg;
    const int qk = qrem - qj * NTg;
    const int di = offsets_ijk[row * 3 + 0];
    const int dj = offsets_ijk[row * 3 + 1];
    const int dk = offsets_ijk[row * 3 + 2];
    const int I = (qi + di) % NXg;
    const int J = (qj + dj) % NYg;
    int T = qk + dk; T = T < 0 ? 0 : (T > NTg - 1 ? NTg - 1 : T);
    const int nb = I * (NYg * NTg) + J * NTg + T;
    const float qx = coords[q * 3 + 0], qy = coords[q * 3 + 1], qz = coords[q * 3 + 2];
    const float nx_ = coords[nb * 3 + 0], ny_ = coords[nb * 3 + 1], nz_ = coords[nb * 3 + 2];
    float ax = nx_ - qx + 1.0f; ax -= 2.0f * floorf(ax * 0.5f); ax -= 1.0f;
    float ay = ny_ - qy + 1.0f; ay -= 2.0f * floorf(ay * 0.5f); ay -= 1.0f;
    const float at = nz_ - qz;
    float tok[6];
    tok[0] = ax * expf(log_gammas[0]);
    tok[1] = ay * expf(log_gammas[1]);
    tok[2] = at * expf(log_gammas[2]);
    tok[3] = vals[nb * 3 + 0];
    tok[4] = vals[nb * 3 + 1];
    tok[5] = vals[nb * 3 + 2];
#pragma unroll
    for (int ci = 0; ci < 32; ++ci) {
      const int c = hf * 32 + ci;
      const float* w = proj_w + c * 6;
      float a = proj_b[c];
      a = fmaf(tok[0], w[0], a); a = fmaf(tok[1], w[1], a);
      a = fmaf(tok[2], w[2], a); a = fmaf(tok[3], w[3], a);
      a = fmaf(tok[4], w[4], a); a = fmaf(tok[5], w[5], a);
      sK[row * 72 + c] = (_Float16)a;
    }
  }
  __syncthreads();

  // X packed registers: pkX[qt][mt*2+h] = (X[f],X[f+1]), f=mt*16+quad*4+2h,
  // column q=(wv*2+qt)*16+l15
  int pkX[2][8];
#pragma unroll
  for (int qt = 0; qt < 2; ++qt) {
    const int q = (wv * 2 + qt) * 16 + l15;
#pragma unroll
    for (int mt = 0; mt < 4; ++mt) {
      int2 t = *(const int2*)(sK + q * 72 + mt * 16 + quad * 4);
      pkX[qt][mt * 2 + 0] = t.x;
      pkX[qt][mt * 2 + 1] = t.y;
    }
  }

  // ---------------- transformer layers ------------------------------------
  for (int l = 0; l < NLAYER; ++l) {
    const _Float16* qkvH = wH + l * 192 * 64;
    const _Float16* woutH = wH + 24576 + l * 64 * 64;
    const _Float16* ff1H = wH + 32768 + l * 128 * 64;
    const _Float16* ff2H = wH + 49152 + l * 64 * 128;
    const float* bqkv = qkv_b + l * 192;

    __syncthreads();  // barrier 1: previous consumers of sK/sV done

    // ---- all-head QKV staging: K,V -> LDS; Q packed in registers ----
    int pkQ[2][8];
    {
      f16x8 bxf[2][2];
#pragma unroll
      for (int qt = 0; qt < 2; ++qt)
#pragma unroll
        for (int kt = 0; kt < 2; ++kt) bxf[qt][kt] = frag_k64(pkX[qt], kt, quad, l15);
#pragma unroll
      for (int hd = 0; hd < NH; ++hd) {
        f32x4 dq[2] = {zero4f(), zero4f()};
        f32x4 dk[2] = {zero4f(), zero4f()};
        f32x4 dv[2] = {zero4f(), zero4f()};
#pragma unroll
        for (int kt = 0; kt < 2; ++kt) {
          f16x8 awq = ld8(qkvH + (hd * 16 + l15) * 64 + kt * 32 + quad * 8);
          f16x8 awk = ld8(qkvH + (64 + hd * 16 + l15) * 64 + kt * 32 + quad * 8);
          f16x8 awv = ld8(qkvH + (128 + hd * 16 + l15) * 64 + kt * 32 + quad * 8);
#pragma unroll
          for (int qt = 0; qt < 2; ++qt) {
            dq[qt] = MFMA16(awq, bxf[qt][kt], dq[qt]);
            dk[qt] = MFMA16(awk, bxf[qt][kt], dk[qt]);
            dv[qt] = MFMA16(awv, bxf[qt][kt], dv[qt]);
          }
        }
        const f32x4 bq4 = *(const f32x4*)(bqkv + hd * 16 + quad * 4);
        const f32x4 bk4 = *(const f32x4*)(bqkv + 64 + hd * 16 + quad * 4);
        const f32x4 bv4 = *(const f32x4*)(bqkv + 128 + hd * 16 + quad * 4);
#pragma unroll
        for (int qt = 0; qt < 2; ++qt) {
          const int q = (wv * 2 + qt) * 16 + l15;
          H4U k4;
          k4.d[0] = pk2(dk[qt][0] + bk4[0], dk[qt][1] + bk4[1]);
          k4.d[1] = pk2(dk[qt][2] + bk4[2], dk[qt][3] + bk4[3]);
          *(f16x4*)(sK + q * 72 + hd * 16 + quad * 4) = k4.v;
#pragma unroll
          for (int jr = 0; jr < 4; ++jr)
            sV[(hd * 16 + quad * 4 + jr) * 136 + q] = (_Float16)(dv[qt][jr] + bv4[jr]);
          pkQ[qt][hd * 2 + 0] = pk2((dq[qt][0] + bq4[0]) * 0.25f, (dq[qt][1] + bq4[1]) * 0.25f);
          pkQ[qt][hd * 2 + 1] = pk2((dq[qt][2] + bq4[2]) * 0.25f, (dq[qt][3] + bq4[3]) * 0.25f);
        }
      }
    }
    __syncthreads();  // barrier 2: K/V visible; attention below is barrier-free

    // ---- attention, stream-fused: scores->exp->PV per key-pair ----
    int pkO[2][8];
#pragma unroll
    for (int hd = 0; hd < NH; ++hd) {
#pragma unroll
      for (int qt = 0; qt < 2; ++qt) {
        f16x8 bqf = frag_k16p(pkQ[qt][hd * 2 + 0], pkQ[qt][hd * 2 + 1], quad, l15);
        float s0 = 0.f;
        f32x4 ov = zero4f();
#pragma unroll
        for (int kt2 = 0; kt2 < 4; ++kt2) {
          int pkP[4];
#pragma unroll
          for (int mi = 0; mi < 2; ++mi) {
            const int mt = kt2 * 2 + mi;
            f16x8 ak = (quad < 2) ? ld8(sK + (mt * 16 + l15) * 72 + hd * 16 + quad * 8)
                                  : zero8();
            f32x4 zc = zero4f();
            f32x4 sc = MFMA16(ak, bqf, zc);
            float e0 = __expf(sc[0]), e1 = __expf(sc[1]);
            float e2 = __expf(sc[2]), e3 = __expf(sc[3]);
            s0 += (e0 + e1) + (e2 + e3);
            pkP[mi * 2 + 0] = pk2(e0, e1);
            pkP[mi * 2 + 1] = pk2(e2, e3);
          }
          f16x8 av = ld8(sV + (hd * 16 + l15) * 136 + kt2 * 32 + quad * 8);
          f16x8 bp = frag_k64(pkP, 0, quad, l15);
          ov = MFMA16(av, bp, ov);
        }
        s0 += __shfl_xor(s0, 16, 64);
        s0 += __shfl_xor(s0, 32, 64);
        const float inv = 1.0f / s0;
        pkO[qt][hd * 2 + 0] = pk2(ov[0] * inv, ov[1] * inv);
        pkO[qt][hd * 2 + 1] = pk2(ov[2] * inv, ov[3] * inv);
      }
    }

    // ---- out-proj (K=64 full GEMM) + residual + LN1 (registers) ----
#pragma unroll
    for (int qt = 0; qt < 2; ++qt) {
      f32x4 y2[4] = {zero4f(), zero4f(), zero4f(), zero4f()};
#pragma unroll
      for (int kt = 0; kt < 2; ++kt) {
        f16x8 bof = frag_k64(pkO[qt], kt, quad, l15);
#pragma unroll
        for (int mt = 0; mt < 4; ++mt) {
          f16x8 aw = ld8(woutH + (mt * 16 + l15) * 64 + kt * 32 + quad * 8);
          y2[mt] = MFMA16(aw, bof, y2[mt]);
        }
      }
      res_ln_qt(y2, pkX[qt], out_b + l * 64, ln1_s + l * 64, ln1_b + l * 64, quad);
    }

    // ---- FF, stream-fused: H-pair = relu(W1 X + b1) -> immediately FF2 ----
#pragma unroll
    for (int qt = 0; qt < 2; ++qt) {
      f16x8 bx2[2];
#pragma unroll
      for (int kt = 0; kt < 2; ++kt) bx2[kt] = frag_k64(pkX[qt], kt, quad, l15);
      const float* b1 = ff1_b + l * 128;
      f32x4 g4[4] = {zero4f(), zero4f(), zero4f(), zero4f()};
#pragma unroll
      for (int kt = 0; kt < 4; ++kt) {
        int pkH[4];
#pragma unroll
        for (int mi = 0; mi < 2; ++mi) {
          const int mt = kt * 2 + mi;
          f32x4 f8 = zero4f();
#pragma unroll
          for (int k2 = 0; k2 < 2; ++k2) {
            f16x8 aw = ld8(ff1H + (mt * 16 + l15) * 64 + k2 * 32 + quad * 8);
            f8 = MFMA16(aw, bx2[k2], f8);
          }
          f32x4 bb = *(const f32x4*)(b1 + mt * 16 + quad * 4);
          pkH[mi * 2 + 0] = pk2(fmaxf(f8[0] + bb[0], 0.f), fmaxf(f8[1] + bb[1], 0.f));
          pkH[mi * 2 + 1] = pk2(fmaxf(f8[2] + bb[2], 0.f), fmaxf(f8[3] + bb[3], 0.f));
        }
        f16x8 bh = frag_k64(pkH, 0, quad, l15);
#pragma unroll
        for (int mt2 = 0; mt2 < 4; ++mt2) {
          f16x8 aw = ld8(ff2H + (mt2 * 16 + l15) * 128 + kt * 32 + quad * 8);
          g4[mt2] = MFMA16(aw, bh, g4[mt2]);
        }
      }
      res_ln_qt(g4, pkX[qt], ff2_b + l * 64, ln2_s + l * 64, ln2_b + l * 64, quad);
    }
  }  // layers

  // ---------------- head: mean over S, LN, gelu-MLP -> 3 outputs ----------
  __syncthreads();  // sK free for scratch
  {
    float* pf = (float*)sK;   // 256 partials
    float* gsc = pf + 256;
    float* asc = gsc + 64;
    // column sums from packed register X: in-lane qt, shfl over l15
    f32x4 cs[4];
#pragma unroll
    for (int mt = 0; mt < 4; ++mt) {
      float2 a0 = up2(pkX[0][mt * 2 + 0]), a1 = up2(pkX[0][mt * 2 + 1]);
      float2 b0 = up2(pkX[1][mt * 2 + 0]), b1 = up2(pkX[1][mt * 2 + 1]);
      cs[mt][0] = a0.x + b0.x;
      cs[mt][1] = a0.y + b0.y;
      cs[mt][2] = a1.x + b1.x;
      cs[mt][3] = a1.y + b1.y;
    }
#pragma unroll
    for (int d = 1; d <= 8; d <<= 1)
#pragma unroll
      for (int mt = 0; mt < 4; ++mt)
#pragma unroll
        for (int jr = 0; jr < 4; ++jr) cs[mt][jr] += __shfl_xor(cs[mt][jr], d, 64);
    if (l15 == 0) {
#pragma unroll
      for (int mt = 0; mt < 4; ++mt)
        *(f32x4*)(pf + wv * 64 + mt * 16 + quad * 4) = cs[mt];
    }
    __syncthreads();
    if (tid < 64) {
      const float hm = (pf[tid] + pf[64 + tid] + pf[128 + tid] + pf[192 + tid]) * (1.0f / 128.0f);
      float t = hm;
      t += __shfl_xor(t, 1, 64);  t += __shfl_xor(t, 2, 64);
      t += __shfl_xor(t, 4, 64);  t += __shfl_xor(t, 8, 64);
      t += __shfl_xor(t, 16, 64); t += __shfl_xor(t, 32, 64);
      const float mu = t * (1.0f / 64.0f);
      const float dv = hm - mu;
      float v2 = dv * dv;
      v2 += __shfl_xor(v2, 1, 64);  v2 += __shfl_xor(v2, 2, 64);
      v2 += __shfl_xor(v2, 4, 64);  v2 += __shfl_xor(v2, 8, 64);
      v2 += __shfl_xor(v2, 16, 64); v2 += __shfl_xor(v2, 32, 64);
      const float var = v2 * (1.0f / 64.0f);
      gsc[tid] = fmaf(dv * rsqrtf(var + EPSf), head_ln_s[tid], head_ln_b[tid]);
    }
    __syncthreads();
    if (tid < 64) {
      float z = head1_b[tid];
      for (int k = 0; k < 64; ++k) z = fmaf(gsc[k], head1_w[tid * 64 + k], z);
      asc[tid] = 0.5f * z * (1.0f + erff(z * 0.70710678118654752f));
    }
    __syncthreads();
    if (tid < 3) {
      float z = head2_b[tid];
      for (int k = 0; k < 64; ++k) z = fmaf(asc[k], head2_w[tid * 64 + k], z);
      out[b * 3 + tid] = z;
    }
  }
}

extern "C" void kernel_launch(void* const* d_in, const int* in_sizes, int n_in,
                              void* d_out, int out_size, void* d_ws, size_t ws_size,
                              hipStream_t stream) {
  (void)n_in; (void)ws_size; (void)out_size;
  const int B = in_sizes[0];
  _Float16* wsH = (_Float16*)d_ws;  // 65536 halves = 128 KB

  prep_weights<<<dim3(256), dim3(256), 0, stream>>>(
      (const float*)d_in[7],   // qkv_w
      (const float*)d_in[9],   // out_w
      (const float*)d_in[13],  // ff1_w
      (const float*)d_in[15],  // ff2_w
      wsH);

  fieldformer_mfma<<<dim3(B), dim3(256), 0, stream>>>(
      (const int*)d_in[0],     // q_lin_idx
      (const int*)d_in[1],     // offsets_ijk
      (const float*)d_in[2],   // coords
      (const float*)d_in[3],   // vals
      (const float*)d_in[4],   // log_gammas
      (const float*)d_in[5],   // proj_w
      (const float*)d_in[6],   // proj_b
      (const float*)d_in[8],   // qkv_b
      (const float*)d_in[10],  // out_b
      (const float*)d_in[11],  // ln1_s
      (const float*)d_in[12],  // ln1_b
      (const float*)d_in[14],  // ff1_b
      (const float*)d_in[16],  // ff2_b
      (const float*)d_in[17],  // ln2_s
      (const float*)d_in[18],  // ln2_b
      (const float*)d_in[19],  // head_ln_s
      (const float*)d_in[20],  // head_ln_b
      (const float*)d_in[21],  // head1_w
      (const float*)d_in[22],  // head1_b
      (const float*)d_in[23],  // head2_w
      (const float*)d_in[24],  // head2_b
      wsH,
      (float*)d_out);
}